// Round 10
// baseline (2716.120 us; speedup 1.0000x reference)
//
#include <hip/hip_runtime.h>
#include <hip/hip_bf16.h>

// Bidirectional LSTM, B=256, S=256, E=300, H=512.
// Persistent scan (PLAIN launch): 256 WGs = 2 dir x 4 batch-tiles(64) x 32 j-tiles(16 h-cols).
// D = W' x h^T via mfma_f32_32x32x16_bf16. A (W') h-part pinned in VGPRs via asm loads,
// xe-part in LDS. h/xe in fragment-native layout [k-slot][b][8].
// h-exchange: group-local. FAST (group XCD-homogeneous, runtime-verified): plain stores +
// sc0 loads -> everything stays in the XCD's L2. SLOW fallback: sc0 sc1 (IF$).
// Per step: [xe MFMAs] -> [poll 32 per-WG flags] -> [cooperative stage of 64KB h tile into
// LDS, one barrier] -> [32 ds_read+MFMA] -> [epilogue, h store, vmcnt drain, barrier, flag].

#define SQ 256
#define NB 256
#define HD 512
#define ED 300
#define KW 832   // 512 + 320
#define G4 2048

typedef __attribute__((ext_vector_type(8))) short bf16x8;
typedef __attribute__((ext_vector_type(16))) float f32x16;
typedef __attribute__((ext_vector_type(4))) int i32x4;
typedef unsigned long long u64;

#define MFMA32 __builtin_amdgcn_mfma_f32_32x32x16_bf16

__device__ __forceinline__ unsigned short f2bf(float x) {
  union { float f; unsigned u; } v; v.f = x;
  unsigned r = v.u + 0x7FFFu + ((v.u >> 16) & 1u);
  return (unsigned short)(r >> 16);
}
__device__ __forceinline__ float sigf(float x) { return 1.f / (1.f + __expf(-x)); }
__device__ __forceinline__ float tanhf_(float x) {
  float t = __expf(-2.f * fabsf(x));
  float r = (1.f - t) / (1.f + t);
  return x < 0.f ? -r : r;
}

__global__ void k_zero(unsigned* __restrict__ p, int n) {
  int i = blockIdx.x * 256 + threadIdx.x;
  if (i < n) p[i] = 0u;
}

// W' bf16 [2][2048][832] = [W_hh | W_ih | 0-pad] per gate row
__global__ void k_prep_w(const float* __restrict__ Wihf, const float* __restrict__ Whhf,
                         const float* __restrict__ Wihb, const float* __restrict__ Whhb,
                         unsigned short* __restrict__ Wp) {
  int idx = blockIdx.x * 256 + threadIdx.x;
  if (idx >= 2 * G4 * KW) return;
  int d = idx / (G4 * KW);
  int rem = idx % (G4 * KW);
  int R = rem / KW, k = rem % KW;
  const float* Whh = d ? Whhb : Whhf;
  const float* Wih = d ? Wihb : Wihf;
  float v = 0.f;
  if (k < HD) v = Whh[R * HD + k];
  else if (k < HD + ED) v = Wih[R * ED + (k - HD)];
  Wp[idx] = f2bf(v);
}

// xeT bf16 [S][20 cx][2 hi][256 b][8] : fragment-native emb[tok] (k = cx*16 + hi*8 + e)
__global__ void k_prep_xe2(const int* __restrict__ x, const float* __restrict__ emb,
                           unsigned short* __restrict__ xeT) {
  const int t = blockIdx.x >> 2, qq = blockIdx.x & 3;
  __shared__ int tok[NB];
  if (threadIdx.x < NB) tok[threadIdx.x] = x[threadIdx.x * SQ + t];
  __syncthreads();
  unsigned short* dst = xeT + (size_t)t * 81920;
  const int u0 = qq * 20480;
  for (int u = u0 + threadIdx.x; u < u0 + 20480; u += 256) {
    const int e = u & 7, b = (u >> 3) & 255, hi = (u >> 11) & 1, cx = u >> 12;
    const int k = cx * 16 + hi * 8 + e;
    float v = (k < ED) ? emb[(size_t)tok[b] * ED + k] : 0.f;
    dst[u] = f2bf(v);
  }
}

// ---- access helpers (all "memory"-clobbered) ----
template<bool FAST>
__device__ __forceinline__ i32x4 ldg16(const unsigned short* p) {
  i32x4 r;
  if constexpr (FAST)
    asm volatile("global_load_dwordx4 %0, %1, off sc0" : "=v"(r) : "v"(p) : "memory");
  else
    asm volatile("global_load_dwordx4 %0, %1, off sc0 sc1" : "=v"(r) : "v"(p) : "memory");
  return r;
}
template<bool FAST>
__device__ __forceinline__ void stg8(u64* p, u64 v) {
  if constexpr (FAST)
    asm volatile("global_store_dwordx2 %0, %1, off" :: "v"(p), "v"(v) : "memory");
  else
    asm volatile("global_store_dwordx2 %0, %1, off sc0 sc1" :: "v"(p), "v"(v) : "memory");
}
template<bool FAST>
__device__ __forceinline__ unsigned ldflag(const unsigned* p) {
  unsigned r;
  if constexpr (FAST)
    asm volatile("global_load_dword %0, %1, off sc0\n\ts_waitcnt vmcnt(0)"
                 : "=v"(r) : "v"(p) : "memory");
  else
    asm volatile("global_load_dword %0, %1, off sc0 sc1\n\ts_waitcnt vmcnt(0)"
                 : "=v"(r) : "v"(p) : "memory");
  return r;
}
template<bool FAST>
__device__ __forceinline__ void stflag(unsigned* p, unsigned v) {
  if constexpr (FAST)
    asm volatile("global_store_dword %0, %1, off" :: "v"(p), "v"(v) : "memory");
  else
    asm volatile("global_store_dword %0, %1, off sc0 sc1" :: "v"(p), "v"(v) : "memory");
}

template<bool FAST>
__device__ void scan_body(const unsigned short* __restrict__ Wp,
                          const unsigned short* __restrict__ xeT,
                          const float* __restrict__ bias,
                          unsigned short* __restrict__ hbufT,  // [2 par][2 d][64 slot][256 b][8]
                          float* __restrict__ hfin,
                          unsigned* __restrict__ flg,
                          unsigned short* hlds,                // LDS 64KB: [64 s][64 bl][8]
                          const unsigned short* wldsX) {       // LDS 40KB: [2 mq][20 cx][64 l][8]
  const int p = blockIdx.x;
  const int g8 = p & 7, d = g8 >> 2, bg = g8 & 3, ct = p >> 3;
  const int tid = threadIdx.x, lane = tid & 63, wv = tid >> 6;
  const int mq = wv >> 1, nq = wv & 1;
  const int hi = lane >> 5, l31 = lane & 31;
  const int b = bg * 64 + nq * 32 + l31;
  const int jbase = ct * 16 + mq * 8 + hi;

  // ---- h-phase A fragments -> registers via asm loads (cannot be rematerialized) ----
  bf16x8 ha[32];
  {
    const int R = (l31 & 3) * HD + ct * 16 + mq * 8 + (l31 >> 2);
    const unsigned short* wr = Wp + ((size_t)d * G4 + R) * KW + hi * 8;
    #pragma unroll
    for (int cc = 0; cc < 32; ++cc) {
      i32x4 v;
      asm volatile("global_load_dwordx4 %0, %1, off" : "=v"(v) : "v"(wr + cc * 16) : "memory");
      ha[cc] = __builtin_bit_cast(bf16x8, v);
    }
    asm volatile("s_waitcnt vmcnt(0)" ::: "memory");
  }
  float br[16];
  #pragma unroll
  for (int r = 0; r < 16; ++r)
    br[r] = bias[(r & 3) * HD + jbase + 2 * (r >> 2)];

  unsigned* fbase = flg + (g8 << 6);
  unsigned* fmine = fbase + ct;
  const unsigned short* wx = wldsX + ((size_t)mq * 1280 + lane) * 8;
  const unsigned short* hrd = hlds + (size_t)(hi * 512 + (nq * 32 + l31) * 8);
  float cst[4] = {0.f, 0.f, 0.f, 0.f};

  for (int t = 0; t < SQ; ++t) {
    const int tx = d ? (SQ - 1 - t) : t;
    f32x16 a0, a1, a2, a3;
    #pragma unroll
    for (int r = 0; r < 16; ++r) { a0[r] = br[r]; a1[r] = 0.f; a2[r] = 0.f; a3[r] = 0.f; }

    // ---- xe phase (k 512..831): h-independent, before the poll ----
    const unsigned short* xb = xeT + (size_t)tx * 81920 + ((size_t)hi * 256 + b) * 8;
    #pragma unroll
    for (int cx = 0; cx < 20; ++cx) {
      bf16x8 bbv = *(const bf16x8*)(xb + cx * 4096);
      bf16x8 aav = *(const bf16x8*)(wx + cx * 512);
      switch (cx & 3) {
        case 0: a0 = MFMA32(aav, bbv, a0, 0, 0, 0); break;
        case 1: a1 = MFMA32(aav, bbv, a1, 0, 0, 0); break;
        case 2: a2 = MFMA32(aav, bbv, a2, 0, 0, 0); break;
        case 3: a3 = MFMA32(aav, bbv, a3, 0, 0, 0); break;
      }
    }

    if (t > 0) {
      // ---- poll the group's 32 per-WG flags (each wave independently) ----
      const unsigned tgt = (unsigned)t;
      while (1) {
        unsigned v = ldflag<FAST>(fbase + l31);
        if (__all((int)(v >= tgt))) break;
        __builtin_amdgcn_s_sleep(1);
      }

      // ---- cooperative stage: 64KB h tile (this group's 64 b x 512 k) -> LDS ----
      const unsigned short* hsrc = hbufT + (size_t)((t & 1) * 2 + d) * 131072 + bg * 512;
      i32x4 sbuf[16];
      #pragma unroll
      for (int i = 0; i < 16; ++i)
        sbuf[i] = ldg16<FAST>(hsrc + (size_t)(i * 4 + wv) * 2048 + lane * 8);
      asm volatile("s_waitcnt vmcnt(0)" ::: "memory");
      #pragma unroll
      for (int i = 0; i < 16; ++i)
        *(bf16x8*)(hlds + (size_t)(i * 256 + tid) * 8) = __builtin_bit_cast(bf16x8, sbuf[i]);
      __syncthreads();   // hT ready for all waves

      // ---- h phase (k 0..511): conflict-free ds_reads + MFMA ----
      #pragma unroll
      for (int j = 0; j < 32; ++j) {
        bf16x8 bbv = *(const bf16x8*)(hrd + (size_t)j * 1024);
        switch (j & 3) {
          case 0: a0 = MFMA32(ha[j], bbv, a0, 0, 0, 0); break;
          case 1: a1 = MFMA32(ha[j], bbv, a1, 0, 0, 0); break;
          case 2: a2 = MFMA32(ha[j], bbv, a2, 0, 0, 0); break;
          case 3: a3 = MFMA32(ha[j], bbv, a3, 0, 0, 0); break;
        }
      }
    }

    // ---- epilogue: all 4 gates local per lane; c in regs ----
    f32x16 ac;
    #pragma unroll
    for (int r = 0; r < 16; ++r) ac[r] = (a0[r] + a1[r]) + (a2[r] + a3[r]);
    float hv[4];
    #pragma unroll
    for (int u = 0; u < 4; ++u) {
      const float I = sigf(ac[4 * u + 0]);
      const float F = sigf(ac[4 * u + 1]);
      const float G = tanhf_(ac[4 * u + 2]);
      const float O = sigf(ac[4 * u + 3]);
      const float c = F * cst[u] + I * G;
      cst[u] = c;
      hv[u] = O * tanhf_(c);
    }
    if (t == SQ - 1) {
      #pragma unroll
      for (int u = 0; u < 4; ++u)
        hfin[((size_t)d * NB + b) * HD + jbase + 2 * u] = hv[u];
    } else {
      // pack (round-9-proven): slot s=ct*2+mq, elems e = hi + 2u; lane(hi) stores its 8B half
      const unsigned d0 = (unsigned)f2bf(hv[0]) | ((unsigned)f2bf(hv[1]) << 16);
      const unsigned d1 = (unsigned)f2bf(hv[2]) | ((unsigned)f2bf(hv[3]) << 16);
      const unsigned pd0 = (unsigned)__shfl_xor((int)d0, 32, 64);
      const unsigned pd1 = (unsigned)__shfl_xor((int)d1, 32, 64);
      const unsigned A = hi ? pd1 : d0;
      const unsigned B = hi ? d1 : pd0;
      const u64 w = (u64)(A & 0xFFFFu) | ((u64)(B & 0xFFFFu) << 16) |
                    ((u64)(A >> 16) << 32) | ((u64)(B >> 16) << 48);
      u64* hout = (u64*)(hbufT + (size_t)(((t & 1) ^ 1) * 2 + d) * 131072 +
                         ((size_t)(ct * 2 + mq) * 256 + b) * 8 + hi * 4);
      stg8<FAST>(hout, w);
      asm volatile("s_waitcnt vmcnt(0)" ::: "memory");   // this wave's h at L2/IF$
      __syncthreads();   // all waves drained; also: all hT ds_reads done before next overwrite
      if (tid == 0) stflag<FAST>(fmine, (unsigned)(t + 1));
    }
  }
}

__global__ __launch_bounds__(256, 1) void lstm_scan(
    const unsigned short* __restrict__ Wp,
    const unsigned short* __restrict__ xeT,
    const float* __restrict__ bias_f,
    const float* __restrict__ bias_b,
    unsigned short* __restrict__ hbufT,
    float* __restrict__ hfin,
    unsigned* __restrict__ flg,      // [8 groups][64]
    unsigned* __restrict__ xcdm,     // [8]
    unsigned* __restrict__ gbar) {   // [1]
  extern __shared__ unsigned short dynlds[];  // [hT 32768 shorts][wldsX 10240 shorts]
  unsigned short* hldsp = dynlds;
  unsigned short* wldsX = dynlds + 32768;
  __shared__ unsigned s_mask;
  const int p = blockIdx.x;
  const int g8 = p & 7;
  const int d  = g8 >> 2;
  const int ct = p >> 3;
  const int tid = threadIdx.x;

  unsigned xcc;
  asm volatile("s_getreg_b32 %0, hwreg(HW_REG_XCC_ID)" : "=s"(xcc));
  if (tid == 0) {
    __hip_atomic_fetch_or(&xcdm[g8], 1u << (xcc & 31),
                          __ATOMIC_RELEASE, __HIP_MEMORY_SCOPE_AGENT);
    __hip_atomic_fetch_add(gbar, 1u, __ATOMIC_ACQ_REL, __HIP_MEMORY_SCOPE_AGENT);
  }

  // stage xe-phase A fragments into LDS
  for (int u = tid; u < 2560; u += 256) {
    const int m = u / 1280, rem = u % 1280;
    const int cx = rem >> 6, l = rem & 63;
    const int rho = l & 31, hiw = l >> 5;
    const int R = (rho & 3) * HD + ct * 16 + m * 8 + (rho >> 2);
    const int k = 512 + cx * 16 + hiw * 8;
    bf16x8 v = *(const bf16x8*)(Wp + ((size_t)d * G4 + R) * KW + k);
    *(bf16x8*)&wldsX[(size_t)u * 8] = v;
  }

  // one-time grid wait (all 256 WGs resident by capacity under plain launch), read XCD mask
  if (tid == 0) {
    while (1) {
      unsigned g;
      asm volatile("global_load_dword %0, %1, off sc0 sc1\n\ts_waitcnt vmcnt(0)"
                   : "=v"(g) : "v"(gbar) : "memory");
      if (g >= 256u) break;
      __builtin_amdgcn_s_sleep(8);
    }
    unsigned mk;
    asm volatile("global_load_dword %0, %1, off sc0 sc1\n\ts_waitcnt vmcnt(0)"
                 : "=v"(mk) : "v"(&xcdm[g8]) : "memory");
    s_mask = mk;
  }
  __syncthreads();

  const float* bias = d ? bias_b : bias_f;
  if (__popc(s_mask) == 1)
    scan_body<true>(Wp, xeT, bias, hbufT, hfin, flg, hldsp, wldsX);
  else
    scan_body<false>(Wp, xeT, bias, hbufT, hfin, flg, hldsp, wldsX);
}

__global__ void k_out(const float* __restrict__ hfin, const float* __restrict__ Wo,
                      const float* __restrict__ bo, float* __restrict__ out) {
  const int b = blockIdx.x;
  const int tid = threadIdx.x;
  float s = 0.f;
  for (int k = tid; k < 1024; k += 256)
    s += hfin[((k >> 9) * NB + b) * HD + (k & 511)] * Wo[k];
  #pragma unroll
  for (int o = 32; o > 0; o >>= 1) s += __shfl_down(s, o, 64);
  __shared__ float red[4];
  if ((tid & 63) == 0) red[tid >> 6] = s;
  __syncthreads();
  if (tid == 0) out[b] = red[0] + red[1] + red[2] + red[3] + bo[0];
}

extern "C" void kernel_launch(void* const* d_in, const int* in_sizes, int n_in,
                              void* d_out, int out_size, void* d_ws, size_t ws_size,
                              hipStream_t stream) {
  const int*   x    = (const int*)d_in[0];
  const float* emb  = (const float*)d_in[1];
  const float* Wihf = (const float*)d_in[2];
  const float* Whhf = (const float*)d_in[3];
  const float* bf   = (const float*)d_in[4];
  const float* Wihb = (const float*)d_in[5];
  const float* Whhb = (const float*)d_in[6];
  const float* bb   = (const float*)d_in[7];
  const float* Wo   = (const float*)d_in[8];
  const float* bo   = (const float*)d_in[9];
  float* out = (float*)d_out;

  // ws layout:
  //   Wp    @ 0          : 6,815,744
  //   xeT   @ 6,815,744  : 41,943,040
  //   hbufT @ 48,758,784 : 1,048,576
  //   flg   @ 49,807,360 : 2,048
  //   xcdm  @ 49,809,408 : 32
  //   gbar  @ 49,809,440 : 16
  //   hfin  @ 49,809,456 : 1,048,576
  char* ws = (char*)d_ws;
  unsigned short* Wp    = (unsigned short*)(ws + 0);
  unsigned short* xeT   = (unsigned short*)(ws + 6815744);
  unsigned short* hbufT = (unsigned short*)(ws + 48758784);
  unsigned*       flg   = (unsigned*)(ws + 49807360);
  unsigned*       xcdm  = (unsigned*)(ws + 49809408);
  unsigned*       gbar  = (unsigned*)(ws + 49809440);
  float*          hfin  = (float*)(ws + 49809456);

  // zero hbufT + flg + xcdm + gbar (48,758,784 .. 49,809,456 = 262,668 words)
  k_zero<<<1027, 256, 0, stream>>>((unsigned*)(ws + 48758784), 262668);
  k_prep_w<<<(2 * G4 * KW + 255) / 256, 256, 0, stream>>>(Wihf, Whhf, Wihb, Whhb, Wp);
  k_prep_xe2<<<SQ * 4, 256, 0, stream>>>(x, emb, xeT);

  const int ldsBytes = 65536 + 40960;  // 106,496
  hipFuncSetAttribute((const void*)lstm_scan,
                      hipFuncAttributeMaxDynamicSharedMemorySize, ldsBytes);

  lstm_scan<<<dim3(256), dim3(256), ldsBytes, stream>>>(Wp, xeT, bf, bb,
                                                        hbufT, hfin, flg, xcdm, gbar);

  k_out<<<NB, 256, 0, stream>>>(hfin, Wo, bo, out);
}